// Round 5
// baseline (475.018 us; speedup 1.0000x reference)
//
#include <hip/hip_runtime.h>
#include <cstddef>

#define NN   32
#define CIN  256
#define COUT 256
#define TT   128
#define VV   25
#define KK   3
#define TV   (TT*VV)        // 3200
#define NTVC (NN*TT*VV)     // 102400
#define BN_EPS 1e-5f

#define YT_LD 104           // yT row stride (shorts): 208 B -> 2-way max (free)
#define XS_LD 264           // xs row stride (shorts): 528 B -> 2-way max (free)

typedef __attribute__((ext_vector_type(8))) short bf16x8;   // 8 bf16 = 4 VGPRs
typedef __attribute__((ext_vector_type(4))) float f32x4;    // MFMA C/D

__device__ __forceinline__ unsigned short f2bf(float f) {
    unsigned int u = __float_as_uint(f);
    u = (u + 0x7fffu + ((u >> 16) & 1u)) >> 16;   // RNE
    return (unsigned short)u;
}

// pack f32x4 -> 4 bf16 (RNE) in one uint2, via v_cvt_pk_bf16_f32
__device__ __forceinline__ uint2 pk4(f32x4 v) {
    uint2 r;
    asm("v_cvt_pk_bf16_f32 %0, %1, %2" : "=v"(r.x) : "v"(v[0]), "v"(v[1]));
    asm("v_cvt_pk_bf16_f32 %0, %1, %2" : "=v"(r.y) : "v"(v[2]), "v"(v[3]));
    return r;
}

// ---------------- K0: W fp32 -> bf16 ----------------
__global__ __launch_bounds__(256)
void convert_w_kernel(const float* __restrict__ W, unsigned short* __restrict__ Wb) {
    int i = blockIdx.x * 256 + threadIdx.x;   // grid = 768 blocks, exact
    Wb[i] = f2bf(W[i]);
}

// ---------------- K1: x [n][c][tv] fp32 -> xT [n][tv][c] bf16 ----------------
__global__ __launch_bounds__(256)
void transpose_x_kernel(const float* __restrict__ x, unsigned short* __restrict__ xT) {
    __shared__ float T[64][65];
    const int n   = blockIdx.z;
    const int s0  = blockIdx.x * 64;   // 50 tiles
    const int c0  = blockIdx.y * 64;   // 4 tiles
    const int tid = threadIdx.x;
    const int r    = tid >> 4;         // 0..15
    const int col4 = (tid & 15) * 4;

    const float* xp = x + (size_t)(n * CIN + c0) * TV + s0;
    for (int rr = r; rr < 64; rr += 16) {
        float4 v = *(const float4*)(xp + (size_t)rr * TV + col4);
        T[rr][col4 + 0] = v.x; T[rr][col4 + 1] = v.y;
        T[rr][col4 + 2] = v.z; T[rr][col4 + 3] = v.w;
    }
    __syncthreads();
    unsigned short* op = xT + ((size_t)n * TV + s0) * CIN + c0;
    for (int ss = r; ss < 64; ss += 16) {
        ushort4 o;
        o.x = f2bf(T[col4 + 0][ss]);
        o.y = f2bf(T[col4 + 1][ss]);
        o.z = f2bf(T[col4 + 2][ss]);
        o.w = f2bf(T[col4 + 3][ss]);
        *(ushort4*)(op + (size_t)ss * CIN + col4) = o;
    }
}

// ---------------- K2: MFMA conv GEMM + MFMA adjacency + fused BN partial sums ----
// r5: block = (n, SINGLE t), 512 threads = 8 waves, with the FULL r3-verified
// structure: xs UNIONED into yT (LDS 53248+6144 = 59392 B, the r3-proven size),
// B1 (stage visible) -> Stage A -> B2 (xs reads done; union becomes yT) ->
// pad-zero + y1 write -> B3 -> Stage B.  The only structural change vs r3 is
// the block split: 8 waves, per-wave o-96 via acc[2][6] (48 acc regs, two-pass
// Stage A keeps live W frags at 24), so TWO blocks co-reside per CU
// (2x59392 B LDS, 2x512 thr, 4 waves/SIMD at ~112 unified regs) and block k+1's
// phase0/StageA overlaps block k's StageB/epilogue.
__global__ __launch_bounds__(512, 4)
void gemm_adj_kernel(const unsigned short* __restrict__ xT,
                     const unsigned short* __restrict__ Wb,
                     const float* __restrict__ A,
                     const float* __restrict__ b,
                     float* __restrict__ y2,
                     float* __restrict__ statsN)
{
    __shared__ __align__(16) unsigned short U[CIN * YT_LD];   // 53248 B: xs then yT
    __shared__ __align__(16) unsigned short Ab[32 * 96];      //  6144 B

    const int tid  = threadIdx.x;
    const int lane = tid & 63;
    const int wg   = tid >> 6;      // wave 0..7
    const int ln15 = lane & 15;
    const int quad = lane >> 4;     // 0..3
    const int t    = blockIdx.x & 127;
    const int n    = blockIdx.x >> 7;

    // ---- phase 0: stage xs rows 0..24 (U as xs), zero rows 25..31, Ab ----
    {
        const unsigned short* xsrc = xT + ((size_t)n * TV + (size_t)t * VV) * CIN;
        for (int ch = tid; ch < 800; ch += 512) {             // 25 rows x 32 chunks
            const int s = ch >> 5, c8 = ch & 31;
            *(bf16x8*)&U[s * XS_LD + c8 * 8] = *(const bf16x8*)&xsrc[ch * 8];
        }
        const bf16x8 z = {0,0,0,0,0,0,0,0};
        for (int ch = tid; ch < 231; ch += 512) {             // zero rows 25..31
            const int rr = 25 + ch / 33, c8 = ch - (ch / 33) * 33;
            *(bf16x8*)&U[rr * XS_LD + c8 * 8] = z;
        }
        for (int i = tid; i < 32 * 96; i += 512) {            // Ab[w][kv]=A[k][v][w], 0-pad
            const int w = i / 96, kv = i - w * 96;
            const int k = kv >> 5, v = kv & 31;
            Ab[i] = f2bf((v < VV && w < VV) ? A[k * VV * VV + v * VV + w] : 0.f);
        }
    }

    // ---- bias folded into acc init (per-o = per-column = per-lane) ----
    f32x4 acc[2][6];
    #pragma unroll
    for (int nt = 0; nt < 6; ++nt) {
        const float bv = b[96 * wg + 16 * nt + ln15];
        #pragma unroll
        for (int mt = 0; mt < 2; ++mt)
            #pragma unroll
            for (int r = 0; r < 4; ++r)
                acc[mt][nt][r] = bv;
    }

    __syncthreads();   // B1: xs + Ab visible

    // ---- Stage A: conv GEMM in two nt-half passes (keeps live W frags at 24) ----
    #pragma unroll
    for (int kp = 0; kp < 2; ++kp) {
        const unsigned short* wp = Wb + (size_t)(96 * wg + 48 * kp + ln15) * CIN + quad * 8;
        bf16x8 wbuf[2][3];
        #pragma unroll
        for (int nt = 0; nt < 3; ++nt)
            wbuf[0][nt] = *(const bf16x8*)(wp + (size_t)nt * 16 * CIN);

        #pragma unroll
        for (int ks = 0; ks < 8; ++ks) {
            const int cur = ks & 1, nxt = cur ^ 1;
            if (ks < 7) {
                #pragma unroll
                for (int nt = 0; nt < 3; ++nt)
                    wbuf[nxt][nt] = *(const bf16x8*)(wp + (size_t)nt * 16 * CIN + (ks + 1) * 32);
            }
            bf16x8 xfr[2];
            #pragma unroll
            for (int mt = 0; mt < 2; ++mt)
                xfr[mt] = *(const bf16x8*)&U[(16 * mt + ln15) * XS_LD + ks * 32 + quad * 8];
            #pragma unroll
            for (int mt = 0; mt < 2; ++mt)
                #pragma unroll
                for (int nt = 0; nt < 3; ++nt)
                    acc[mt][3 * kp + nt] = __builtin_amdgcn_mfma_f32_16x16x32_bf16(
                                      xfr[mt], wbuf[cur][nt], acc[mt][3 * kp + nt], 0, 0, 0);
        }
    }

    __syncthreads();   // B2: all xs reads done -> union region becomes yT

    // zero v-pad slots of yT (v = 25..31 per (c,k))
    for (int i = tid; i < CIN * 21; i += 512) {
        const int c = i / 21, rr = i - c * 21;
        const int k = rr / 7, v = VV + (rr - k * 7);
        U[c * YT_LD + k * 32 + v] = 0;
    }

    // ---- write y1 -> yT[c][k*32+v]  (v = s; single-t so no h-loop) ----
    //  mt0 (s 0..15):  all quads, v0 = 4*quad          -> b64
    //  mt1 (s 16..31): quads 0,1: v0 = 16+4*quad       -> b64
    //                  quad 2:    r0 only, v = 24      -> b16
    //                  quad 2 r>=1 / quad 3: zero pads -> skip
    {
        const int obase = 96 * wg + ln15;
        {
            const int v0 = quad * 4;
            #pragma unroll
            for (int nt = 0; nt < 6; ++nt) {
                const int o = obase + 16 * nt;
                *(uint2*)&U[(o & 255) * YT_LD + (o >> 8) * 32 + v0] = pk4(acc[0][nt]);
            }
        }
        if (quad < 2) {
            const int v0 = 16 + quad * 4;
            #pragma unroll
            for (int nt = 0; nt < 6; ++nt) {
                const int o = obase + 16 * nt;
                *(uint2*)&U[(o & 255) * YT_LD + (o >> 8) * 32 + v0] = pk4(acc[1][nt]);
            }
        } else if (quad == 2) {
            #pragma unroll
            for (int nt = 0; nt < 6; ++nt) {
                const int o = obase + 16 * nt;
                U[(o & 255) * YT_LD + (o >> 8) * 32 + 24] = f2bf(acc[1][nt][0]);
            }
        }
    }

    __syncthreads();   // B3: yT complete (data + pads)

    // ---- Stage B: adjacency via MFMA; each wave owns c-blocks {32wg, 32wg+16} ----
    bf16x8 bq[3][2];
    #pragma unroll
    for (int k = 0; k < 3; ++k)
        #pragma unroll
        for (int nw = 0; nw < 2; ++nw)
            bq[k][nw] = *(const bf16x8*)&Ab[(16 * nw + ln15) * 96 + k * 32 + quad * 8];

    #pragma unroll
    for (int cbi = 0; cbi < 2; ++cbi) {
        const int cb = wg * 32 + cbi * 16;
        f32x4 a2[2];
        #pragma unroll
        for (int nw = 0; nw < 2; ++nw)
            #pragma unroll
            for (int r = 0; r < 4; ++r) a2[nw][r] = 0.f;
        #pragma unroll
        for (int k = 0; k < 3; ++k) {
            const bf16x8 af = *(const bf16x8*)&U[(cb + ln15) * YT_LD + k * 32 + quad * 8];
            a2[0] = __builtin_amdgcn_mfma_f32_16x16x32_bf16(af, bq[k][0], a2[0], 0, 0, 0);
            a2[1] = __builtin_amdgcn_mfma_f32_16x16x32_bf16(af, bq[k][1], a2[1], 0, 0, 0);
        }
        // store: element (c = cb+4*quad+r, w = 16*nw+ln15), w < 25; BN partial sums
        float* op = y2 + (size_t)n * COUT * TV
                       + (size_t)(cb + 4 * quad) * TV + (size_t)t * VV;
        float bsum1[4], bsum2[4];
        #pragma unroll
        for (int r = 0; r < 4; ++r) {
            const float va = a2[0][r];
            const float vb = a2[1][r];
            op[r * TV + ln15] = va;
            if (ln15 < 9) op[r * TV + 16 + ln15] = vb;
            const float vbm = (ln15 < 9) ? vb : 0.f;
            bsum1[r] = va + vbm;
            bsum2[r] = va * va + vbm * vbm;
        }
        // reduce over the 16 w-lanes, 1 atomic per (n,c)
        #pragma unroll
        for (int r = 0; r < 4; ++r) {
            float s1 = bsum1[r], s2 = bsum2[r];
            #pragma unroll
            for (int off = 1; off < 16; off <<= 1) {
                s1 += __shfl_xor(s1, off);
                s2 += __shfl_xor(s2, off);
            }
            if (ln15 == 0) {
                const int c = cb + 4 * quad + r;
                atomicAdd(&statsN[n * 512 + c], s1);
                atomicAdd(&statsN[n * 512 + 256 + c], s2);
            }
        }
    }
}

// ---------------- K3: per-n stats -> scale/shift ----------------
__global__ void bn_stats_kernel(const float* __restrict__ statsN,
                                const float* __restrict__ gamma,
                                const float* __restrict__ beta,
                                float* __restrict__ ss)
{
    int c = threadIdx.x;
    float s1 = 0.f, s2 = 0.f;
    for (int g = 0; g < NN; ++g) {
        s1 += statsN[g * 512 + c];
        s2 += statsN[g * 512 + 256 + c];
    }
    float mu  = s1 * (1.f / NTVC);
    float var = s2 * (1.f / NTVC) - mu * mu;
    float sc  = gamma[c] * rsqrtf(var + BN_EPS);
    ss[c]        = sc;
    ss[COUT + c] = beta[c] - mu * sc;
}

// ---------------- K4: normalize + ReLU in place ----------------
__global__ __launch_bounds__(256)
void bn_apply_kernel(float* __restrict__ y, const float* __restrict__ ss)
{
    int i = blockIdx.x * 256 + threadIdx.x;
    int f = i * 4;
    int cch = (f / TV) & (COUT - 1);
    float sc = ss[cch], sh = ss[COUT + cch];
    float4 v = ((float4*)y)[i];
    v.x = fmaxf(v.x * sc + sh, 0.f);
    v.y = fmaxf(v.y * sc + sh, 0.f);
    v.z = fmaxf(v.z * sc + sh, 0.f);
    v.w = fmaxf(v.w * sc + sh, 0.f);
    ((float4*)y)[i] = v;
}

extern "C" void kernel_launch(void* const* d_in, const int* in_sizes, int n_in,
                              void* d_out, int out_size, void* d_ws, size_t ws_size,
                              hipStream_t stream)
{
    const float* x     = (const float*)d_in[0];
    const float* A     = (const float*)d_in[1];
    const float* W     = (const float*)d_in[2];
    const float* b     = (const float*)d_in[3];
    const float* gamma = (const float*)d_in[4];
    const float* beta  = (const float*)d_in[5];
    float* out = (float*)d_out;

    // ws layout (bytes): [0,65536) statsN[n][2][256]  [65536,67584) scale/shift
    //                    [67584, +393216) W bf16
    //                    [460800, +52428800) xT bf16
    float* statsN = (float*)d_ws;
    float* ss     = (float*)((char*)d_ws + 65536);
    unsigned short* Wb  = (unsigned short*)((char*)d_ws + 67584);
    unsigned short* xTb = (unsigned short*)((char*)d_ws + 67584 + (size_t)KK * COUT * CIN * 2);

    hipMemsetAsync(statsN, 0, (size_t)NN * 512 * sizeof(float), stream);

    convert_w_kernel<<<(KK * COUT * CIN) / 256, 256, 0, stream>>>(W, Wb);
    transpose_x_kernel<<<dim3(TV / 64, CIN / 64, NN), 256, 0, stream>>>(x, xTb);
    gemm_adj_kernel<<<NN * TT, 512, 0, stream>>>(xTb, Wb, A, b, out, statsN);
    bn_stats_kernel<<<1, 256, 0, stream>>>(statsN, gamma, beta, ss);
    bn_apply_kernel<<<(NN * COUT * TT * VV) / (4 * 256), 256, 0, stream>>>(out, ss);
}

// Round 6
// 374.224 us; speedup vs baseline: 1.2693x; 1.2693x over previous
//
#include <hip/hip_runtime.h>
#include <cstddef>

#define NN   32
#define CIN  256
#define COUT 256
#define TT   128
#define VV   25
#define KK   3
#define TV   (TT*VV)        // 3200
#define NTVC (NN*TT*VV)     // 102400
#define BN_EPS 1e-5f

#define YT_LD 104           // yT row stride (shorts): 208 B -> 2-way max (free)
#define XS_LD 264           // xs row stride (shorts): 528 B -> 2-way max (free)

typedef __attribute__((ext_vector_type(8))) short bf16x8;   // 8 bf16 = 4 VGPRs
typedef __attribute__((ext_vector_type(4))) float f32x4;    // MFMA C/D

__device__ __forceinline__ unsigned short f2bf(float f) {
    unsigned int u = __float_as_uint(f);
    u = (u + 0x7fffu + ((u >> 16) & 1u)) >> 16;   // RNE
    return (unsigned short)u;
}

// pack f32x4 -> 4 bf16 (RNE) in one uint2, via v_cvt_pk_bf16_f32
__device__ __forceinline__ uint2 pk4(f32x4 v) {
    uint2 r;
    asm("v_cvt_pk_bf16_f32 %0, %1, %2" : "=v"(r.x) : "v"(v[0]), "v"(v[1]));
    asm("v_cvt_pk_bf16_f32 %0, %1, %2" : "=v"(r.y) : "v"(v[2]), "v"(v[3]));
    return r;
}

// ---------------- K0: W fp32 -> bf16 ----------------
__global__ __launch_bounds__(256)
void convert_w_kernel(const float* __restrict__ W, unsigned short* __restrict__ Wb) {
    int i = blockIdx.x * 256 + threadIdx.x;   // grid = 768 blocks, exact
    Wb[i] = f2bf(W[i]);
}

// ---------------- K1: MFMA conv GEMM + MFMA adjacency + fused BN partial sums ----
// r6 = verified r3 (1024 thr, 16 waves, t-pair blocks, union LDS 59392 B,
// 5 barriers, 2-slot W dbuf, soff {0,16,25,41}) with ONE change: the x
// transpose is FUSED into phase 0.  Each block reads its own x tile fp32
// directly (256 c-rows x 25 float2, coalesced), converts in-register, and
// scatters bf16 into the same padded xs layout.  transpose_x_kernel deleted
// (-209 MB pipeline traffic, +105 MB read here, one fewer pass).
__global__ __launch_bounds__(1024)
void gemm_adj_kernel(const float* __restrict__ x,
                     const unsigned short* __restrict__ Wb,
                     const float* __restrict__ A,
                     const float* __restrict__ b,
                     float* __restrict__ y2,
                     float* __restrict__ statsN)
{
    __shared__ __align__(16) unsigned short U[CIN * YT_LD];   // 53248 B: xs then yT
    __shared__ __align__(16) unsigned short Ab[32 * 96];      //  6144 B

    const int tid  = threadIdx.x;
    const int lane = tid & 63;
    const int wg   = tid >> 6;      // wave 0..15
    const int ln15 = lane & 15;
    const int quad = lane >> 4;     // 0..3
    const int tp   = blockIdx.x & 63;
    const int n    = blockIdx.x >> 6;
    const int t0   = tp * 2;

    // ---- phase 0: fused transpose x -> xs (rows 0..49), zero pad rows, Ab ----
    {
        const float* xb = x + (size_t)n * CIN * TV + (size_t)t0 * VV;
        for (int wi = tid; wi < 6400; wi += 1024) {           // 256 c-rows x 25 float2
            const int c = wi / 25, j = wi - c * 25;
            const float2 v = *(const float2*)(xb + (size_t)c * TV + 2 * j);
            const int s = 2 * j;                              // 0,2,..,48
            U[s * XS_LD + c]       = f2bf(v.x);
            U[(s + 1) * XS_LD + c] = f2bf(v.y);
        }
        const bf16x8 z = {0,0,0,0,0,0,0,0};
        for (int ch = tid; ch < 231; ch += 1024) {            // zero rows 50..56
            const int rr = 50 + ch / 33, c8 = ch - (ch / 33) * 33;
            *(bf16x8*)&U[rr * XS_LD + c8 * 8] = z;
        }
        for (int i = tid; i < 32 * 96; i += 1024) {           // Ab[w][kv]=A[k][v][w], 0-pad
            const int w = i / 96, kv = i - w * 96;
            const int k = kv >> 5, v = kv & 31;
            Ab[i] = f2bf((v < VV && w < VV) ? A[k * VV * VV + v * VV + w] : 0.f);
        }
    }

    // ---- bias folded into acc init (per-o = per-column = per-lane) ----
    f32x4 acc[4][3];
    #pragma unroll
    for (int nt = 0; nt < 3; ++nt) {
        const float bv = b[48 * wg + 16 * nt + ln15];
        #pragma unroll
        for (int mt = 0; mt < 4; ++mt)
            #pragma unroll
            for (int r = 0; r < 4; ++r)
                acc[mt][nt][r] = bv;
    }

    __syncthreads();   // B1: xs + Ab visible

    // ---- Stage A: conv GEMM, x from LDS, W double-buffered from L2 ----
    const int soff[4] = {0, 16, 25, 41};
    const unsigned short* wp = Wb + (size_t)(48 * wg + ln15) * CIN + quad * 8;
    bf16x8 wbuf[2][3];
    #pragma unroll
    for (int nt = 0; nt < 3; ++nt)
        wbuf[0][nt] = *(const bf16x8*)(wp + (size_t)nt * 16 * CIN);

    #pragma unroll
    for (int ks = 0; ks < 8; ++ks) {
        const int cur = ks & 1, nxt = cur ^ 1;
        if (ks < 7) {
            #pragma unroll
            for (int nt = 0; nt < 3; ++nt)
                wbuf[nxt][nt] = *(const bf16x8*)(wp + (size_t)nt * 16 * CIN + (ks + 1) * 32);
        }
        bf16x8 xfr[4];
        #pragma unroll
        for (int mt = 0; mt < 4; ++mt)
            xfr[mt] = *(const bf16x8*)&U[(soff[mt] + ln15) * XS_LD + ks * 32 + quad * 8];
        #pragma unroll
        for (int mt = 0; mt < 4; ++mt)
            #pragma unroll
            for (int nt = 0; nt < 3; ++nt)
                acc[mt][nt] = __builtin_amdgcn_mfma_f32_16x16x32_bf16(
                                  xfr[mt], wbuf[cur][nt], acc[mt][nt], 0, 0, 0);
    }

    __syncthreads();   // B2: all xs reads done -> union region becomes yT

    // zero v-pad slots of yT (v = 25..31 per (c,k))
    for (int i = tid; i < CIN * 21; i += 1024) {
        const int c = i / 21, rr = i - c * 21;
        const int k = rr / 7, v = VV + (rr - k * 7);
        U[c * YT_LD + k * 32 + v] = 0;
    }

    const int obase = 48 * wg + ln15;

    // write one t'-half of y1 into yT[c][k*32+v]; h selects acc tiles {2h, 2h+1}
    //  full tile  (soff 0 / 25):  all quads, v0 = 4*quad        -> b64
    //  partial    (soff 16 / 41): quads 0,1: v0 = 16+4*quad     -> b64
    //                             quad 2:    r0 only, v = 24    -> b16
    //                             quad 2 r>=1 / quad 3: t'-dup or pad -> skip
    auto write_half = [&](int h) {
        const int mtF = 2 * h, mtP = 2 * h + 1;
        {
            const int v0 = quad * 4;
            #pragma unroll
            for (int nt = 0; nt < 3; ++nt) {
                const int o = obase + 16 * nt;
                *(uint2*)&U[(o & 255) * YT_LD + (o >> 8) * 32 + v0] = pk4(acc[mtF][nt]);
            }
        }
        if (quad < 2) {
            const int v0 = 16 + quad * 4;
            #pragma unroll
            for (int nt = 0; nt < 3; ++nt) {
                const int o = obase + 16 * nt;
                *(uint2*)&U[(o & 255) * YT_LD + (o >> 8) * 32 + v0] = pk4(acc[mtP][nt]);
            }
        } else if (quad == 2) {
            #pragma unroll
            for (int nt = 0; nt < 3; ++nt) {
                const int o = obase + 16 * nt;
                U[(o & 255) * YT_LD + (o >> 8) * 32 + 24] = f2bf(acc[mtP][nt][0]);
            }
        }
    };

    bf16x8 bq[3][2];
    float bsum1[4], bsum2[4];
    #pragma unroll
    for (int r = 0; r < 4; ++r) { bsum1[r] = 0.f; bsum2[r] = 0.f; }
    const int cb = wg * 16;     // each wave owns one 16-c block

    #pragma unroll
    for (int h = 0; h < 2; ++h) {
        if (h) __syncthreads();          // B4: half-0 yT reads done
        write_half(h);
        __syncthreads();                 // B3/B5: yT half (+pads for h=0) ready

        if (h == 0) {
            #pragma unroll
            for (int k = 0; k < 3; ++k)
                #pragma unroll
                for (int nw = 0; nw < 2; ++nw)
                    bq[k][nw] = *(const bf16x8*)&Ab[(16 * nw + ln15) * 96 + k * 32 + quad * 8];
        }

        f32x4 a2[2];
        #pragma unroll
        for (int nw = 0; nw < 2; ++nw)
            #pragma unroll
            for (int r = 0; r < 4; ++r) a2[nw][r] = 0.f;
        #pragma unroll
        for (int k = 0; k < 3; ++k) {
            const bf16x8 af = *(const bf16x8*)&U[(cb + ln15) * YT_LD + k * 32 + quad * 8];
            a2[0] = __builtin_amdgcn_mfma_f32_16x16x32_bf16(af, bq[k][0], a2[0], 0, 0, 0);
            a2[1] = __builtin_amdgcn_mfma_f32_16x16x32_bf16(af, bq[k][1], a2[1], 0, 0, 0);
        }
        // store: element (c = cb+4*quad+r, w = 16*nw+ln15), w < 25; BN partial sums
        const int t = t0 + h;
        float* op = y2 + (size_t)n * COUT * TV
                       + (size_t)(cb + 4 * quad) * TV + (size_t)t * VV;
        #pragma unroll
        for (int r = 0; r < 4; ++r) {
            const float va = a2[0][r];
            const float vb = a2[1][r];
            op[r * TV + ln15] = va;
            if (ln15 < 9) op[r * TV + 16 + ln15] = vb;
            const float vbm = (ln15 < 9) ? vb : 0.f;
            bsum1[r] += va + vbm;
            bsum2[r] += va * va + vbm * vbm;
        }
    }

    // ---- fused BN partial reduction: sum over 16 w-lanes, 1 atomic per (n,c) ----
    #pragma unroll
    for (int r = 0; r < 4; ++r) {
        float s1 = bsum1[r], s2 = bsum2[r];
        #pragma unroll
        for (int off = 1; off < 16; off <<= 1) {
            s1 += __shfl_xor(s1, off);
            s2 += __shfl_xor(s2, off);
        }
        if (ln15 == 0) {
            const int c = cb + 4 * quad + r;
            atomicAdd(&statsN[n * 512 + c], s1);
            atomicAdd(&statsN[n * 512 + 256 + c], s2);
        }
    }
}

// ---------------- K2: per-n stats -> scale/shift ----------------
__global__ void bn_stats_kernel(const float* __restrict__ statsN,
                                const float* __restrict__ gamma,
                                const float* __restrict__ beta,
                                float* __restrict__ ss)
{
    int c = threadIdx.x;
    float s1 = 0.f, s2 = 0.f;
    for (int g = 0; g < NN; ++g) {
        s1 += statsN[g * 512 + c];
        s2 += statsN[g * 512 + 256 + c];
    }
    float mu  = s1 * (1.f / NTVC);
    float var = s2 * (1.f / NTVC) - mu * mu;
    float sc  = gamma[c] * rsqrtf(var + BN_EPS);
    ss[c]        = sc;
    ss[COUT + c] = beta[c] - mu * sc;
}

// ---------------- K3: normalize + ReLU in place ----------------
__global__ __launch_bounds__(256)
void bn_apply_kernel(float* __restrict__ y, const float* __restrict__ ss)
{
    int i = blockIdx.x * 256 + threadIdx.x;
    int f = i * 4;
    int cch = (f / TV) & (COUT - 1);
    float sc = ss[cch], sh = ss[COUT + cch];
    float4 v = ((float4*)y)[i];
    v.x = fmaxf(v.x * sc + sh, 0.f);
    v.y = fmaxf(v.y * sc + sh, 0.f);
    v.z = fmaxf(v.z * sc + sh, 0.f);
    v.w = fmaxf(v.w * sc + sh, 0.f);
    ((float4*)y)[i] = v;
}

extern "C" void kernel_launch(void* const* d_in, const int* in_sizes, int n_in,
                              void* d_out, int out_size, void* d_ws, size_t ws_size,
                              hipStream_t stream)
{
    const float* x     = (const float*)d_in[0];
    const float* A     = (const float*)d_in[1];
    const float* W     = (const float*)d_in[2];
    const float* b     = (const float*)d_in[3];
    const float* gamma = (const float*)d_in[4];
    const float* beta  = (const float*)d_in[5];
    float* out = (float*)d_out;

    // ws layout (bytes): [0,65536) statsN[n][2][256]  [65536,67584) scale/shift
    //                    [67584, +393216) W bf16      (no xT anymore)
    float* statsN = (float*)d_ws;
    float* ss     = (float*)((char*)d_ws + 65536);
    unsigned short* Wb = (unsigned short*)((char*)d_ws + 67584);

    hipMemsetAsync(statsN, 0, (size_t)NN * 512 * sizeof(float), stream);

    convert_w_kernel<<<(KK * COUT * CIN) / 256, 256, 0, stream>>>(W, Wb);
    gemm_adj_kernel<<<NN * (TT / 2), 1024, 0, stream>>>(x, Wb, A, b, out, statsN);
    bn_stats_kernel<<<1, 256, 0, stream>>>(statsN, gamma, beta, ss);
    bn_apply_kernel<<<(NN * COUT * TT * VV) / (4 * 256), 256, 0, stream>>>(out, ss);
}

// Round 7
// 363.574 us; speedup vs baseline: 1.3065x; 1.0293x over previous
//
#include <hip/hip_runtime.h>
#include <cstddef>

#define NN   32
#define CIN  256
#define COUT 256
#define TT   128
#define VV   25
#define KK   3
#define TV   (TT*VV)        // 3200
#define NTVC (NN*TT*VV)     // 102400
#define BN_EPS 1e-5f

#define YT_LD 104           // yT row stride (shorts): 208 B -> 2-way max (free)
#define XS_LD 264           // xs row stride (shorts): 528 B -> 2-way max (free)

typedef __attribute__((ext_vector_type(8))) short bf16x8;   // 8 bf16 = 4 VGPRs
typedef __attribute__((ext_vector_type(4))) float f32x4;    // MFMA C/D

__device__ __forceinline__ unsigned short f2bf(float f) {
    unsigned int u = __float_as_uint(f);
    u = (u + 0x7fffu + ((u >> 16) & 1u)) >> 16;   // RNE
    return (unsigned short)u;
}

// pack f32x4 -> 4 bf16 (RNE) in one uint2, via v_cvt_pk_bf16_f32
__device__ __forceinline__ uint2 pk4(f32x4 v) {
    uint2 r;
    asm("v_cvt_pk_bf16_f32 %0, %1, %2" : "=v"(r.x) : "v"(v[0]), "v"(v[1]));
    asm("v_cvt_pk_bf16_f32 %0, %1, %2" : "=v"(r.y) : "v"(v[2]), "v"(v[3]));
    return r;
}

// ---------------- K0: W fp32 -> bf16 ----------------
__global__ __launch_bounds__(256)
void convert_w_kernel(const float* __restrict__ W, unsigned short* __restrict__ Wb) {
    int i = blockIdx.x * 256 + threadIdx.x;   // grid = 768 blocks, exact
    Wb[i] = f2bf(W[i]);
}

// ---------------- K1: MFMA conv GEMM + MFMA adjacency + fused BN partial sums ----
// r7 = r6 (verified) with phase0 latency-chain compression ONLY:
//  (a) x loads batched: 7 predicated float2 issued back-to-back into regs,
//      then converted/scattered (was a rolled loop serializing ~7 round-trips)
//  (b) Ab loads batched the same way (3 x 1024 = 3072 exact)
//  (c) first W fragments loaded BEFORE B1 (global-only, no LDS dependence)
// Layout, sync structure, index math byte-identical to r6.
__global__ __launch_bounds__(1024)
void gemm_adj_kernel(const float* __restrict__ x,
                     const unsigned short* __restrict__ Wb,
                     const float* __restrict__ A,
                     const float* __restrict__ b,
                     float* __restrict__ y2,
                     float* __restrict__ statsN)
{
    __shared__ __align__(16) unsigned short U[CIN * YT_LD];   // 53248 B: xs then yT
    __shared__ __align__(16) unsigned short Ab[32 * 96];      //  6144 B

    const int tid  = threadIdx.x;
    const int lane = tid & 63;
    const int wg   = tid >> 6;      // wave 0..15
    const int ln15 = lane & 15;
    const int quad = lane >> 4;     // 0..3
    const int tp   = blockIdx.x & 63;
    const int n    = blockIdx.x >> 6;
    const int t0   = tp * 2;

    // ---- phase 0: batched loads first (x, A), then converts/writes ----
    const float* xb = x + (size_t)n * CIN * TV + (size_t)t0 * VV;
    float2 xv[7];
    #pragma unroll
    for (int i = 0; i < 7; ++i) {               // 6400 items over 1024 threads
        const int wi = tid + i * 1024;
        if (wi < 6400) {
            const int c = wi / 25, j = wi - c * 25;
            xv[i] = *(const float2*)(xb + (size_t)c * TV + 2 * j);
        }
    }
    float av[3];
    #pragma unroll
    for (int i = 0; i < 3; ++i) {               // 3072 items, exact
        const int idx = tid + i * 1024;
        const int w = idx / 96, kv = idx - w * 96;
        const int k = kv >> 5, v = kv & 31;
        av[i] = (v < VV && w < VV) ? A[k * VV * VV + v * VV + w] : 0.f;
    }

    // (c) first W fragments: global-only, hoisted above B1
    const unsigned short* wp = Wb + (size_t)(48 * wg + ln15) * CIN + quad * 8;
    bf16x8 wbuf[2][3];
    #pragma unroll
    for (int nt = 0; nt < 3; ++nt)
        wbuf[0][nt] = *(const bf16x8*)(wp + (size_t)nt * 16 * CIN);

    // now the LDS writes
    #pragma unroll
    for (int i = 0; i < 7; ++i) {
        const int wi = tid + i * 1024;
        if (wi < 6400) {
            const int c = wi / 25, j = wi - c * 25;
            const int s = 2 * j;                              // 0,2,..,48
            U[s * XS_LD + c]       = f2bf(xv[i].x);
            U[(s + 1) * XS_LD + c] = f2bf(xv[i].y);
        }
    }
    {
        const bf16x8 z = {0,0,0,0,0,0,0,0};
        for (int ch = tid; ch < 231; ch += 1024) {            // zero rows 50..56
            const int rr = 50 + ch / 33, c8 = ch - (ch / 33) * 33;
            *(bf16x8*)&U[rr * XS_LD + c8 * 8] = z;
        }
        #pragma unroll
        for (int i = 0; i < 3; ++i)
            Ab[tid + i * 1024] = f2bf(av[i]);
    }

    // ---- bias folded into acc init (per-o = per-column = per-lane) ----
    f32x4 acc[4][3];
    #pragma unroll
    for (int nt = 0; nt < 3; ++nt) {
        const float bv = b[48 * wg + 16 * nt + ln15];
        #pragma unroll
        for (int mt = 0; mt < 4; ++mt)
            #pragma unroll
            for (int r = 0; r < 4; ++r)
                acc[mt][nt][r] = bv;
    }

    __syncthreads();   // B1: xs + Ab visible

    // ---- Stage A: conv GEMM, x from LDS, W double-buffered from L2 ----
    const int soff[4] = {0, 16, 25, 41};

    #pragma unroll
    for (int ks = 0; ks < 8; ++ks) {
        const int cur = ks & 1, nxt = cur ^ 1;
        if (ks < 7) {
            #pragma unroll
            for (int nt = 0; nt < 3; ++nt)
                wbuf[nxt][nt] = *(const bf16x8*)(wp + (size_t)nt * 16 * CIN + (ks + 1) * 32);
        }
        bf16x8 xfr[4];
        #pragma unroll
        for (int mt = 0; mt < 4; ++mt)
            xfr[mt] = *(const bf16x8*)&U[(soff[mt] + ln15) * XS_LD + ks * 32 + quad * 8];
        #pragma unroll
        for (int mt = 0; mt < 4; ++mt)
            #pragma unroll
            for (int nt = 0; nt < 3; ++nt)
                acc[mt][nt] = __builtin_amdgcn_mfma_f32_16x16x32_bf16(
                                  xfr[mt], wbuf[cur][nt], acc[mt][nt], 0, 0, 0);
    }

    __syncthreads();   // B2: all xs reads done -> union region becomes yT

    // zero v-pad slots of yT (v = 25..31 per (c,k))
    for (int i = tid; i < CIN * 21; i += 1024) {
        const int c = i / 21, rr = i - c * 21;
        const int k = rr / 7, v = VV + (rr - k * 7);
        U[c * YT_LD + k * 32 + v] = 0;
    }

    const int obase = 48 * wg + ln15;

    // write one t'-half of y1 into yT[c][k*32+v]; h selects acc tiles {2h, 2h+1}
    //  full tile  (soff 0 / 25):  all quads, v0 = 4*quad        -> b64
    //  partial    (soff 16 / 41): quads 0,1: v0 = 16+4*quad     -> b64
    //                             quad 2:    r0 only, v = 24    -> b16
    //                             quad 2 r>=1 / quad 3: t'-dup or pad -> skip
    auto write_half = [&](int h) {
        const int mtF = 2 * h, mtP = 2 * h + 1;
        {
            const int v0 = quad * 4;
            #pragma unroll
            for (int nt = 0; nt < 3; ++nt) {
                const int o = obase + 16 * nt;
                *(uint2*)&U[(o & 255) * YT_LD + (o >> 8) * 32 + v0] = pk4(acc[mtF][nt]);
            }
        }
        if (quad < 2) {
            const int v0 = 16 + quad * 4;
            #pragma unroll
            for (int nt = 0; nt < 3; ++nt) {
                const int o = obase + 16 * nt;
                *(uint2*)&U[(o & 255) * YT_LD + (o >> 8) * 32 + v0] = pk4(acc[mtP][nt]);
            }
        } else if (quad == 2) {
            #pragma unroll
            for (int nt = 0; nt < 3; ++nt) {
                const int o = obase + 16 * nt;
                U[(o & 255) * YT_LD + (o >> 8) * 32 + 24] = f2bf(acc[mtP][nt][0]);
            }
        }
    };

    bf16x8 bq[3][2];
    float bsum1[4], bsum2[4];
    #pragma unroll
    for (int r = 0; r < 4; ++r) { bsum1[r] = 0.f; bsum2[r] = 0.f; }
    const int cb = wg * 16;     // each wave owns one 16-c block

    #pragma unroll
    for (int h = 0; h < 2; ++h) {
        if (h) __syncthreads();          // B4: half-0 yT reads done
        write_half(h);
        __syncthreads();                 // B3/B5: yT half (+pads for h=0) ready

        if (h == 0) {
            #pragma unroll
            for (int k = 0; k < 3; ++k)
                #pragma unroll
                for (int nw = 0; nw < 2; ++nw)
                    bq[k][nw] = *(const bf16x8*)&Ab[(16 * nw + ln15) * 96 + k * 32 + quad * 8];
        }

        f32x4 a2[2];
        #pragma unroll
        for (int nw = 0; nw < 2; ++nw)
            #pragma unroll
            for (int r = 0; r < 4; ++r) a2[nw][r] = 0.f;
        #pragma unroll
        for (int k = 0; k < 3; ++k) {
            const bf16x8 af = *(const bf16x8*)&U[(cb + ln15) * YT_LD + k * 32 + quad * 8];
            a2[0] = __builtin_amdgcn_mfma_f32_16x16x32_bf16(af, bq[k][0], a2[0], 0, 0, 0);
            a2[1] = __builtin_amdgcn_mfma_f32_16x16x32_bf16(af, bq[k][1], a2[1], 0, 0, 0);
        }
        // store: element (c = cb+4*quad+r, w = 16*nw+ln15), w < 25; BN partial sums
        const int t = t0 + h;
        float* op = y2 + (size_t)n * COUT * TV
                       + (size_t)(cb + 4 * quad) * TV + (size_t)t * VV;
        #pragma unroll
        for (int r = 0; r < 4; ++r) {
            const float va = a2[0][r];
            const float vb = a2[1][r];
            op[r * TV + ln15] = va;
            if (ln15 < 9) op[r * TV + 16 + ln15] = vb;
            const float vbm = (ln15 < 9) ? vb : 0.f;
            bsum1[r] += va + vbm;
            bsum2[r] += va * va + vbm * vbm;
        }
    }

    // ---- fused BN partial reduction: sum over 16 w-lanes, 1 atomic per (n,c) ----
    #pragma unroll
    for (int r = 0; r < 4; ++r) {
        float s1 = bsum1[r], s2 = bsum2[r];
        #pragma unroll
        for (int off = 1; off < 16; off <<= 1) {
            s1 += __shfl_xor(s1, off);
            s2 += __shfl_xor(s2, off);
        }
        if (ln15 == 0) {
            const int c = cb + 4 * quad + r;
            atomicAdd(&statsN[n * 512 + c], s1);
            atomicAdd(&statsN[n * 512 + 256 + c], s2);
        }
    }
}

// ---------------- K2: per-n stats -> scale/shift ----------------
__global__ void bn_stats_kernel(const float* __restrict__ statsN,
                                const float* __restrict__ gamma,
                                const float* __restrict__ beta,
                                float* __restrict__ ss)
{
    int c = threadIdx.x;
    float s1 = 0.f, s2 = 0.f;
    for (int g = 0; g < NN; ++g) {
        s1 += statsN[g * 512 + c];
        s2 += statsN[g * 512 + 256 + c];
    }
    float mu  = s1 * (1.f / NTVC);
    float var = s2 * (1.f / NTVC) - mu * mu;
    float sc  = gamma[c] * rsqrtf(var + BN_EPS);
    ss[c]        = sc;
    ss[COUT + c] = beta[c] - mu * sc;
}

// ---------------- K3: normalize + ReLU in place ----------------
__global__ __launch_bounds__(256)
void bn_apply_kernel(float* __restrict__ y, const float* __restrict__ ss)
{
    int i = blockIdx.x * 256 + threadIdx.x;
    int f = i * 4;
    int cch = (f / TV) & (COUT - 1);
    float sc = ss[cch], sh = ss[COUT + cch];
    float4 v = ((float4*)y)[i];
    v.x = fmaxf(v.x * sc + sh, 0.f);
    v.y = fmaxf(v.y * sc + sh, 0.f);
    v.z = fmaxf(v.z * sc + sh, 0.f);
    v.w = fmaxf(v.w * sc + sh, 0.f);
    ((float4*)y)[i] = v;
}

extern "C" void kernel_launch(void* const* d_in, const int* in_sizes, int n_in,
                              void* d_out, int out_size, void* d_ws, size_t ws_size,
                              hipStream_t stream)
{
    const float* x     = (const float*)d_in[0];
    const float* A     = (const float*)d_in[1];
    const float* W     = (const float*)d_in[2];
    const float* b     = (const float*)d_in[3];
    const float* gamma = (const float*)d_in[4];
    const float* beta  = (const float*)d_in[5];
    float* out = (float*)d_out;

    // ws layout (bytes): [0,65536) statsN[n][2][256]  [65536,67584) scale/shift
    //                    [67584, +393216) W bf16      (no xT anymore)
    float* statsN = (float*)d_ws;
    float* ss     = (float*)((char*)d_ws + 65536);
    unsigned short* Wb = (unsigned short*)((char*)d_ws + 67584);

    hipMemsetAsync(statsN, 0, (size_t)NN * 512 * sizeof(float), stream);

    convert_w_kernel<<<(KK * COUT * CIN) / 256, 256, 0, stream>>>(W, Wb);
    gemm_adj_kernel<<<NN * (TT / 2), 1024, 0, stream>>>(x, Wb, A, b, out, statsN);
    bn_stats_kernel<<<1, 256, 0, stream>>>(statsN, gamma, beta, ss);
    bn_apply_kernel<<<(NN * COUT * TT * VV) / (4 * 256), 256, 0, stream>>>(out, ss);
}